// Round 3
// baseline (674.930 us; speedup 1.0000x reference)
//
#include <hip/hip_runtime.h>
#include <math.h>

#define D_ 1024
#define THREE_D 3072
#define B_ 32
#define T_ 2048

// ---------------------------------------------------------------------------
// K1: LayerNorm over concat([raw_g, spec_g, rel_g]) per batch.
// Writes normalized result TRANSPOSED: gnT[k*32 + b].
// Also zeroes pre_alpha[b] and the finish counter[b].
// ---------------------------------------------------------------------------
__global__ __launch_bounds__(256) void ln_kernel(
    const float* __restrict__ raw_g, const float* __restrict__ spec_g,
    const float* __restrict__ rel_g, const float* __restrict__ gamma,
    const float* __restrict__ beta, float* __restrict__ gnT,
    float* __restrict__ pre_alpha, int* __restrict__ cnt) {
  const int b = blockIdx.x;
  const int tid = threadIdx.x;
  __shared__ float sg[THREE_D];
  __shared__ float red[8];
  __shared__ float stats[2];

  if (tid == 0) { pre_alpha[b] = 0.f; cnt[b] = 0; }

  float s = 0.f, s2 = 0.f;
#pragma unroll
  for (int i = 0; i < 12; ++i) {
    int k = i * 256 + tid;
    float v;
    if (k < 1024)       v = raw_g[b * 1024 + k];
    else if (k < 2048)  v = spec_g[b * 1024 + (k - 1024)];
    else                v = rel_g[b * 1024 + (k - 2048)];
    sg[k] = v;
    s += v;
    s2 += v * v;
  }
#pragma unroll
  for (int off = 32; off; off >>= 1) {
    s  += __shfl_down(s, off, 64);
    s2 += __shfl_down(s2, off, 64);
  }
  const int wv = tid >> 6;
  if ((tid & 63) == 0) { red[wv] = s; red[4 + wv] = s2; }
  __syncthreads();
  if (tid == 0) {
    float ts  = red[0] + red[1] + red[2] + red[3];
    float ts2 = red[4] + red[5] + red[6] + red[7];
    float mu  = ts * (1.0f / THREE_D);
    float var = ts2 * (1.0f / THREE_D) - mu * mu;
    stats[0] = mu;
    stats[1] = rsqrtf(var + 1e-5f);
  }
  __syncthreads();
  const float mu = stats[0], rstd = stats[1];
#pragma unroll
  for (int i = 0; i < 12; ++i) {
    int k = i * 256 + tid;
    gnT[k * 32 + b] = (sg[k] - mu) * rstd * gamma[k] + beta[k];
  }
}

// ---------------------------------------------------------------------------
// K2: partial GEMM  h_pre[b][j] = sum_k gnT[k][b] * w1[k][j]
// Grid (16 jt, 16 by), 512 threads = 8 waves. Wave w: khalf = w>>1 picks one
// of 4 48-wide k slices of this block's 192-k range; bhalf = w&1 picks 16 of
// the 32 batches. gnT tile staged in LDS; 48 w1 values prefetched (48
// independent HBM loads in flight). w1 read exactly once.
// partials layout: [slice' = kslice*2+bhalf][16 b][1024 j] f32 (8 MB).
// ---------------------------------------------------------------------------
__global__ __launch_bounds__(512) void gate_gemm(
    const float* __restrict__ gnT, const float* __restrict__ w1,
    float* __restrict__ partials) {
  const int tid   = threadIdx.x;
  const int lane  = tid & 63;
  const int wvid  = tid >> 6;        // 0..7
  const int khalf = wvid >> 1;       // 0..3
  const int bhalf = wvid & 1;        // 0..1
  const int jt = blockIdx.x;         // 0..15
  const int by = blockIdx.y;         // 0..15
  const int j  = jt * 64 + lane;
  const int kslice = by * 4 + khalf; // 0..63, 48 k each

  __shared__ float sg[192 * 32];     // 24 KB: gnT rows [by*192, by*192+192)
  const float* gsrc = gnT + by * 192 * 32;
#pragma unroll
  for (int i = 0; i < 12; ++i) sg[i * 512 + tid] = gsrc[i * 512 + tid];
  __syncthreads();

  const float* wrow = w1 + (size_t)kslice * 48 * D_ + j;
  float w[48];
#pragma unroll
  for (int kk = 0; kk < 48; ++kk) w[kk] = wrow[(size_t)kk * D_];

  float4 acc[4];
#pragma unroll
  for (int i = 0; i < 4; ++i) acc[i] = make_float4(0.f, 0.f, 0.f, 0.f);

  const float4* gp = (const float4*)(sg + (khalf * 48) * 32 + bhalf * 16);
#pragma unroll
  for (int kk = 0; kk < 48; ++kk) {
    const float4* g = gp + kk * 8;   // 32 floats per k row
    const float wv_ = w[kk];
#pragma unroll
    for (int i = 0; i < 4; ++i) {
      float4 gv = g[i];              // wave-uniform -> LDS broadcast
      acc[i].x = fmaf(gv.x, wv_, acc[i].x);
      acc[i].y = fmaf(gv.y, wv_, acc[i].y);
      acc[i].z = fmaf(gv.z, wv_, acc[i].z);
      acc[i].w = fmaf(gv.w, wv_, acc[i].w);
    }
  }

  float* base = partials + ((size_t)(kslice * 2 + bhalf) * 16) * D_ + j;
#pragma unroll
  for (int i = 0; i < 4; ++i) {
    base[(4 * i + 0) * D_] = acc[i].x;
    base[(4 * i + 1) * D_] = acc[i].y;
    base[(4 * i + 2) * D_] = acc[i].z;
    base[(4 * i + 3) * D_] = acc[i].w;
  }
}

// ---------------------------------------------------------------------------
// K3: reduce 64 k-slices, +b1, exact GELU, dot with w2 -> atomicAdd into
// pre_alpha[b]. The LAST of the 4 blocks per b (counter) computes
// sigmoid(total + b2) and writes the final alpha output slot. 5th kernel gone.
// ---------------------------------------------------------------------------
__global__ __launch_bounds__(256) void gate_finish(
    const float* __restrict__ partials, const float* __restrict__ b1,
    const float* __restrict__ w2, const float* __restrict__ b2,
    float* __restrict__ pre_alpha, int* __restrict__ cnt,
    float* __restrict__ alpha_out) {
  const int jc  = blockIdx.x;        // 0..3
  const int b   = blockIdx.y;        // 0..31
  const int tid = threadIdx.x;
  const int j   = jc * 256 + tid;
  const int bh  = b >> 4, br = b & 15;

  const float* p = partials + ((size_t)bh * 16 + br) * D_ + j;
  float s = b1[j];
#pragma unroll 8
  for (int sl = 0; sl < 64; ++sl)
    s += p[(size_t)sl * 32768];      // coalesced across tid
  float h = 0.5f * s * (1.0f + erff(s * 0.7071067811865476f));
  float c = h * w2[j];

#pragma unroll
  for (int off = 32; off; off >>= 1) c += __shfl_down(c, off, 64);
  __shared__ float red[4];
  if ((tid & 63) == 0) red[tid >> 6] = c;
  __syncthreads();
  if (tid == 0) {
    atomicAdd(&pre_alpha[b], red[0] + red[1] + red[2] + red[3]);
    __threadfence();
    int old = atomicAdd(&cnt[b], 1);
    if (old == 3) {                  // last block for this b
      float tot = atomicAdd(&pre_alpha[b], 0.f) + b2[0];  // coherent read
      alpha_out[b] = 1.0f / (1.0f + expf(-tot));
    }
  }
}

// ---------------------------------------------------------------------------
// K4: main_repr = raw_residual + alpha[b] * rel_residual  (memory-bound).
// m13-style linear grid-stride: 2048 blocks x 256 thr, stride 2^19 f4 ==
// exactly one batch, so the step index IS the batch index. 8 f4 loads in
// flight per step-group, plain float4 stores (NT stores regressed in R2).
// ---------------------------------------------------------------------------
__global__ __launch_bounds__(256) void fuse_kernel(
    const float4* __restrict__ raw, const float4* __restrict__ rel,
    const float* __restrict__ alpha, float4* __restrict__ out) {
  const size_t tid0 = (size_t)blockIdx.x * 256 + threadIdx.x;  // < 524288
  const size_t S = (size_t)T_ * D_ / 4;                        // 524288 f4 = 1 batch

#pragma unroll
  for (int s8 = 0; s8 < 8; ++s8) {
    const int s = s8 * 4;
    const size_t i0 = tid0 + (size_t)(s + 0) * S;
    const size_t i1 = tid0 + (size_t)(s + 1) * S;
    const size_t i2 = tid0 + (size_t)(s + 2) * S;
    const size_t i3 = tid0 + (size_t)(s + 3) * S;
    const float a0 = alpha[s + 0], a1 = alpha[s + 1];
    const float a2 = alpha[s + 2], a3 = alpha[s + 3];

    float4 r0 = raw[i0], e0 = rel[i0];
    float4 r1 = raw[i1], e1 = rel[i1];
    float4 r2 = raw[i2], e2 = rel[i2];
    float4 r3 = raw[i3], e3 = rel[i3];

    float4 o0, o1, o2, o3;
    o0.x = fmaf(a0, e0.x, r0.x); o0.y = fmaf(a0, e0.y, r0.y);
    o0.z = fmaf(a0, e0.z, r0.z); o0.w = fmaf(a0, e0.w, r0.w);
    o1.x = fmaf(a1, e1.x, r1.x); o1.y = fmaf(a1, e1.y, r1.y);
    o1.z = fmaf(a1, e1.z, r1.z); o1.w = fmaf(a1, e1.w, r1.w);
    o2.x = fmaf(a2, e2.x, r2.x); o2.y = fmaf(a2, e2.y, r2.y);
    o2.z = fmaf(a2, e2.z, r2.z); o2.w = fmaf(a2, e2.w, r2.w);
    o3.x = fmaf(a3, e3.x, r3.x); o3.y = fmaf(a3, e3.y, r3.y);
    o3.z = fmaf(a3, e3.z, r3.z); o3.w = fmaf(a3, e3.w, r3.w);

    out[i0] = o0; out[i1] = o1; out[i2] = o2; out[i3] = o3;
  }
}

extern "C" void kernel_launch(void* const* d_in, const int* in_sizes, int n_in,
                              void* d_out, int out_size, void* d_ws, size_t ws_size,
                              hipStream_t stream) {
  const float* raw_res = (const float*)d_in[0];
  const float* rel_res = (const float*)d_in[1];
  const float* raw_g   = (const float*)d_in[2];
  const float* spec_g  = (const float*)d_in[3];
  const float* rel_g   = (const float*)d_in[4];
  const float* gamma   = (const float*)d_in[5];
  const float* beta    = (const float*)d_in[6];
  const float* w1      = (const float*)d_in[7];
  const float* b1      = (const float*)d_in[8];
  const float* w2      = (const float*)d_in[9];
  const float* b2      = (const float*)d_in[10];

  float* out = (float*)d_out;
  // Scratch inside d_out's main region; fuse overwrites it afterwards.
  //   gnT:       out[0 .. 98303]
  //   pre_alpha: out[100000 .. 100031]
  //   cnt:       out[100064 .. 100095] (int)
  //   partials:  out[131072 .. 2228223]
  //   alpha:     out[67108864 .. 67108895]  (real output slot, never clobbered)
  float* gnT       = out;
  float* pre_alpha = out + 100000;
  int*   cnt       = (int*)(out + 100064);
  float* partials  = out + 131072;
  float* alpha     = out + (size_t)B_ * T_ * D_;   // 67108864

  ln_kernel<<<dim3(B_), dim3(256), 0, stream>>>(raw_g, spec_g, rel_g, gamma, beta,
                                                gnT, pre_alpha, cnt);
  gate_gemm<<<dim3(16, 16), dim3(512), 0, stream>>>(gnT, w1, partials);
  gate_finish<<<dim3(4, B_), dim3(256), 0, stream>>>(partials, b1, w2, b2,
                                                     pre_alpha, cnt, alpha);
  fuse_kernel<<<dim3(2048), dim3(256), 0, stream>>>(
      (const float4*)raw_res, (const float4*)rel_res, alpha, (float4*)d_out);
}